// Round 1
// baseline (180.214 us; speedup 1.0000x reference)
//
#include <hip/hip_runtime.h>
#include <cmath>

// Problem constants
#define Bsz 32
#define Lsz 256
#define Asz 20
#define PAD 21          // LDS row stride: 21 coprime with 32 banks -> gather ~conflict-free
#define NCHUNK 4        // p-chunks per i
#define PCH 64          // L / NCHUNK
#define GRP 8           // blocks staged per group (8*400 = 3200 floats)
#define NGRP (PCH/GRP)  // 8 groups per chunk
#define BLK1 640        // one thread per (b,j): 32*20

// Workspace offsets (in floats). Total = 710,688 floats = 2.85 MB.
#define OFF_G 0                                  // [NCHUNK][B][L][A] p>i gather partials
#define OFF_C (NCHUNK*Bsz*Lsz*Asz)               // [NCHUNK][L][A]  b-independent (p<=i) partials
#define OFF_E (OFF_C + NCHUNK*Lsz*Asz)           // [NCHUNK][B][L]  energy pair partials
#define OFF_RSQ (OFF_E + NCHUNK*Bsz*Lsz)         // [1024] per-wg sum w^2
#define OFF_RAB (OFF_RSQ + Lsz*NCHUNK)           // [1024] per-wg sum |w|
#define OFF_K2  (OFF_RAB + Lsz*NCHUNK)           // [32]   per-wg (lse - energy) partials

// Kernel 1: stream all of w_pair once. wg = (i, chunk c). Stages 8 blocks of
// 400 floats at a time into padded LDS; accumulates reg sums during staging;
// gathers per-(b,j) logit sums (p>i), energy pair sums (all p), and the
// b-independent p<=i logit contributions.
__global__ __launch_bounds__(BLK1) void k1(const int* __restrict__ x,
                                           const float* __restrict__ wp,
                                           float* __restrict__ ws) {
  const int wg = blockIdx.x;
  const int c = wg & (NCHUNK - 1);
  const int i = wg >> 2;
  const int t = threadIdx.x;
  const int b = t / Asz;        // 0..31
  const int j = t - b * Asz;    // 0..19

  __shared__ float blk[GRP * Asz * PAD];   // 8 * 420 floats
  __shared__ int   xs[Bsz * PCH];          // x[b, p] for this chunk
  __shared__ int   xi[Bsz];                // x[b, i]
  __shared__ float red1[BLK1];
  __shared__ float red2[BLK1];

  const int pbase = c * PCH;
  for (int k = t; k < Bsz * PCH; k += BLK1) {
    int bb = k >> 6, pp = k & 63;
    xs[k] = x[bb * Lsz + pbase + pp];
  }
  if (t < Bsz) xi[t] = x[t * Lsz + i];
  __syncthreads();

  float accJ = 0.f;   // sum_{p>i} blk[j*20 + x[b,p]]   (per-(b,j))
  float accE = 0.f;   // sum_p blk[x[b,i]*20 + x[b,p]]  (j==0 lanes)
  float accC = 0.f;   // p<i: blk[j*20+19]; p==i: blk[j*21]  (t<20 lanes)
  float rsq = 0.f, rab = 0.f;

  const float* wrow = wp + (size_t)(i * Lsz + pbase) * (Asz * Asz);

  // prefetch group 0 into registers
  float v0, v1, v2, v3, v4;
  {
    const float* g0 = wrow;
    v0 = g0[t]; v1 = g0[t + BLK1]; v2 = g0[t + 2*BLK1];
    v3 = g0[t + 3*BLK1]; v4 = g0[t + 4*BLK1];
  }

  for (int g = 0; g < NGRP; ++g) {
    // write current group's registers into padded LDS + reg-stat accumulate
    {
      float vv[5] = {v0, v1, v2, v3, v4};
      #pragma unroll
      for (int k = 0; k < 5; ++k) {
        float v = vv[k];
        rsq += v * v;
        rab += fabsf(v);
        int o = k * BLK1 + t;        // 0..3199 within group
        int bi = o / 400;            // block within group
        int w = o - bi * 400;
        int r = w / 20;
        int col = w - r * 20;
        blk[bi * (Asz * PAD) + r * PAD + col] = v;
      }
    }
    __syncthreads();

    // issue next group's global loads before the gather (latency overlap)
    if (g + 1 < NGRP) {
      const float* ns = wrow + (g + 1) * (GRP * 400);
      v0 = ns[t]; v1 = ns[t + BLK1]; v2 = ns[t + 2*BLK1];
      v3 = ns[t + 3*BLK1]; v4 = ns[t + 4*BLK1];
    }

    const int p0 = pbase + g * GRP;
    #pragma unroll
    for (int pp = 0; pp < GRP; ++pp) {
      const int p = p0 + pp;
      const float* bb = blk + pp * (Asz * PAD);
      const int xv = xs[b * PCH + (p - pbase)];   // broadcast read
      if (p > i) accJ += bb[j * PAD + xv];
      if (j == 0) accE += bb[xi[b] * PAD + xv];
      if (t < Asz) {
        if (p < i)       accC += bb[t * PAD + 19];
        else if (p == i) accC += bb[t * PAD + t];
      }
    }
    __syncthreads();
  }

  ws[OFF_G + (((size_t)c * Bsz + b) * Lsz + i) * Asz + j] = accJ;
  if (j == 0) ws[OFF_E + (c * Bsz + b) * Lsz + i] = accE;
  if (t < Asz) ws[OFF_C + (c * Lsz + i) * Asz + t] = accC;

  red1[t] = rsq; red2[t] = rab;
  __syncthreads();
  for (int s = 320; s >= 5; s >>= 1) {
    if (t < s) { red1[t] += red1[t + s]; red2[t] += red2[t + s]; }
    __syncthreads();
  }
  if (t == 0) {
    ws[OFF_RSQ + wg] = red1[0] + red1[1] + red1[2] + red1[3] + red1[4];
    ws[OFF_RAB + wg] = red2[0] + red2[1] + red2[2] + red2[3] + red2[4];
  }
}

// Kernel 2: one thread per (b,i) row: assemble 20 logits, logsumexp, subtract
// energy, block-reduce to 32 partials.
__global__ __launch_bounds__(256) void k2(const int* __restrict__ x,
                                          const float* __restrict__ wsingle,
                                          const float* __restrict__ ws,
                                          float* __restrict__ wso) {
  const int t = threadIdx.x;
  const int row = blockIdx.x * 256 + t;
  const int b = row >> 8;
  const int i = row & 255;

  float logits[Asz];
  float m = -1e30f;
  #pragma unroll
  for (int j = 0; j < Asz; ++j) {
    float v = wsingle[i * Asz + j];
    #pragma unroll
    for (int c = 0; c < NCHUNK; ++c) {
      v += ws[OFF_C + (c * Lsz + i) * Asz + j];
      v += ws[OFF_G + (((size_t)c * Bsz + b) * Lsz + i) * Asz + j];
    }
    logits[j] = v;
    m = fmaxf(m, v);
  }
  float se = 0.f;
  #pragma unroll
  for (int j = 0; j < Asz; ++j) se += expf(logits[j] - m);
  float lse = m + logf(se);

  float en = wsingle[i * Asz + x[b * Lsz + i]];
  #pragma unroll
  for (int c = 0; c < NCHUNK; ++c) en += ws[OFF_E + (c * Bsz + b) * Lsz + i];

  float val = lse - en;
  __shared__ float red[256];
  red[t] = val;
  __syncthreads();
  for (int s = 128; s >= 1; s >>= 1) {
    if (t < s) red[t] += red[t + s];
    __syncthreads();
  }
  if (t == 0) wso[OFF_K2 + blockIdx.x] = red[0];
}

// Kernel 3: final scalar: mean energy term + single reg/lasso + pair reg/lasso.
__global__ __launch_bounds__(256) void k3(const float* __restrict__ wsingle,
                                          const float* __restrict__ ws,
                                          float* __restrict__ out) {
  const int t = threadIdx.x;
  float ssq = 0.f, sab = 0.f;
  for (int k = t; k < Lsz * Asz; k += 256) {
    float v = wsingle[k];
    ssq += v * v; sab += fabsf(v);
  }
  float psq = 0.f, pab = 0.f;
  for (int k = t; k < Lsz * NCHUNK; k += 256) {
    psq += ws[OFF_RSQ + k];
    pab += ws[OFF_RAB + k];
  }
  float fe = 0.f;
  if (t < 32) fe = ws[OFF_K2 + t];

  const float LP = (float)(0.2 * 255.0);  // LAMBDA_PAIR = 0.2*(L-1)
  float val = fe * (1.0f / Bsz) + (ssq + sab) + LP * (psq + pab);

  __shared__ float red[256];
  red[t] = val;
  __syncthreads();
  for (int s = 128; s >= 1; s >>= 1) {
    if (t < s) red[t] += red[t + s];
    __syncthreads();
  }
  if (t == 0) out[0] = red[0];
}

extern "C" void kernel_launch(void* const* d_in, const int* in_sizes, int n_in,
                              void* d_out, int out_size, void* d_ws, size_t ws_size,
                              hipStream_t stream) {
  const int*   x       = (const int*)d_in[0];
  const float* wsingle = (const float*)d_in[1];
  const float* wpair   = (const float*)d_in[2];
  float* ws  = (float*)d_ws;
  float* out = (float*)d_out;

  k1<<<Lsz * NCHUNK, BLK1, 0, stream>>>(x, wpair, ws);
  k2<<<(Bsz * Lsz) / 256, 256, 0, stream>>>(x, wsingle, ws, ws);
  k3<<<1, 256, 0, stream>>>(wsingle, ws, out);
}

// Round 2
// 178.129 us; speedup vs baseline: 1.0117x; 1.0117x over previous
//
#include <hip/hip_runtime.h>
#include <cmath>

// Problem constants
#define Bsz 32
#define Lsz 256
#define Asz 20
#define NCHUNK 8        // p-chunks per i (32 p each)
#define PCH 32          // L / NCHUNK
#define GRP 16          // blocks staged per LDS group (16*400 = 6400 floats)
#define NGRP 2          // groups per chunk
#define BLK1 640        // t = j*32 + b  (j=t>>5 in 0..19, b=t&31)

// Workspace offsets (floats). Total ~1.43M floats = 5.7 MB.
#define OFF_G 0                                    // [c][i][b][j] p>i gather partials
#define OFF_C (NCHUNK*Lsz*Bsz*Asz)                 // [c][i][j]    b-independent (p<=i)
#define OFF_E (OFF_C + NCHUNK*Lsz*Asz)             // [c][i][b]    energy pair partials
#define OFF_RSQ (OFF_E + NCHUNK*Lsz*Bsz)           // [2048] per-wg sum w^2
#define OFF_RAB (OFF_RSQ + NCHUNK*Lsz)             // [2048] per-wg sum |w|
#define OFF_K2  (OFF_RAB + NCHUNK*Lsz)             // [L*B]  per-(i,b) lse-energy

// Kernel 1: stream all of w_pair once. wg = (i, chunk c), grid 2048.
// Raw (unpadded) LDS block layout; lane map t=j*32+b makes the gather
// conflict-free (<=40 consecutive words per wave -> 2-way max, free).
__global__ __launch_bounds__(BLK1, 8) void k1(const int* __restrict__ x,
                                              const float* __restrict__ wp,
                                              float* __restrict__ ws) {
  const int wg = blockIdx.x;
  const int c = wg & (NCHUNK - 1);
  const int i = wg >> 3;
  const int t = threadIdx.x;
  const int j = t >> 5;         // 0..19
  const int b = t & 31;         // 0..31

  __shared__ float blk[GRP * 400];   // 25.6 KB
  __shared__ int   xs[PCH * Bsz];    // [dp][b] -> bank = b, conflict-free
  __shared__ int   xi[Bsz];
  __shared__ float wred[32];

  const int pbase = c * PCH;
  for (int k = t; k < PCH * Bsz; k += BLK1) {
    int dp = k >> 5, bb = k & 31;
    xs[k] = x[bb * Lsz + pbase + dp];
  }
  if (t < Bsz) xi[t] = x[t * Lsz + i];

  float accJ = 0.f, accE = 0.f, accC = 0.f, rsq = 0.f, rab = 0.f;

  // chunk = 12800 floats = 3200 float4; group = 1600 float4
  const float4* wrow = (const float4*)(wp + (size_t)(i * Lsz + pbase) * 400);
  float4 v0 = wrow[t];
  float4 v1 = wrow[t + 640];
  float4 v2 = (t < 320) ? wrow[t + 1280] : make_float4(0.f, 0.f, 0.f, 0.f);

  for (int g = 0; g < NGRP; ++g) {
    // stage current group: contiguous b128 writes, no index math
    float4* bf4 = (float4*)blk;
    bf4[t] = v0;
    bf4[t + 640] = v1;
    if (t < 320) bf4[t + 1280] = v2;
    rsq += v0.x*v0.x + v0.y*v0.y + v0.z*v0.z + v0.w*v0.w;
    rsq += v1.x*v1.x + v1.y*v1.y + v1.z*v1.z + v1.w*v1.w;
    rab += fabsf(v0.x)+fabsf(v0.y)+fabsf(v0.z)+fabsf(v0.w);
    rab += fabsf(v1.x)+fabsf(v1.y)+fabsf(v1.z)+fabsf(v1.w);
    if (t < 320) {
      rsq += v2.x*v2.x + v2.y*v2.y + v2.z*v2.z + v2.w*v2.w;
      rab += fabsf(v2.x)+fabsf(v2.y)+fabsf(v2.z)+fabsf(v2.w);
    }
    __syncthreads();

    // prefetch next group (register path overlaps barrier+gather)
    if (g == 0) {
      v0 = wrow[1600 + t];
      v1 = wrow[1600 + t + 640];
      if (t < 320) v2 = wrow[1600 + t + 1280];
    }

    const int p0 = pbase + g * GRP;   // global p of LDS block 0
    // --- accJ: p > i, all waves, uniform trip count ---
    int ppstart = i + 1 - p0;
    if (ppstart < 0) ppstart = 0;
    const int jbase = j * Asz;
    for (int pp = ppstart; pp < GRP; ++pp) {
      int xv = xs[((g * GRP + pp) << 5) | b];
      accJ += blk[pp * 400 + jbase + xv];
    }
    // --- accE (lanes 0..31 of wave 0): all p ---
    if (t < Bsz) {
      const int ebase = xi[t] * Asz;
      for (int pp = 0; pp < GRP; ++pp) {
        int xv = xs[((g * GRP + pp) << 5) | t];
        accE += blk[pp * 400 + ebase + xv];
      }
    } else if (t < Bsz + Asz) {
      // --- accC (lanes 32..51 of wave 0): p<i -> col 19; p==i -> diag ---
      const int jj = t - Bsz;
      int pend = i - p0;
      if (pend > GRP) pend = GRP;
      for (int pp = 0; pp < pend; ++pp) accC += blk[pp * 400 + jj * Asz + 19];
      const int pd = i - p0;
      if (pd >= 0 && pd < GRP) accC += blk[pd * 400 + jj * Asz + jj];
    }
    __syncthreads();
  }

  ws[OFF_G + ((size_t)(c * Lsz + i) * Bsz + b) * Asz + j] = accJ;
  if (t < Bsz) ws[OFF_E + (c * Lsz + i) * Bsz + t] = accE;
  else if (t < Bsz + Asz) ws[OFF_C + (c * Lsz + i) * Asz + (t - Bsz)] = accC;

  // reg-stat reduction: wave shuffle then tiny LDS pass
  for (int s = 32; s >= 1; s >>= 1) {
    rsq += __shfl_down(rsq, s);
    rab += __shfl_down(rab, s);
  }
  if ((t & 63) == 0) { wred[t >> 6] = rsq; wred[16 + (t >> 6)] = rab; }
  __syncthreads();
  if (t == 0) {
    float a = 0.f, bb = 0.f;
    for (int w = 0; w < 10; ++w) { a += wred[w]; bb += wred[16 + w]; }
    ws[OFF_RSQ + wg] = a;
    ws[OFF_RAB + wg] = bb;
  }
}

// Kernel 2: one block per i (640 threads, t=j*32+b): assemble logits,
// logsumexp per (b), subtract energy, write per-(i,b) partial.
__global__ __launch_bounds__(BLK1) void k2(const int* __restrict__ x,
                                           const float* __restrict__ wsng,
                                           const float* __restrict__ ws,
                                           float* __restrict__ wso) {
  const int i = blockIdx.x;
  const int t = threadIdx.x;
  const int j = t >> 5, b = t & 31;
  __shared__ float l[Bsz * 21];

  float v = wsng[i * Asz + j];
  #pragma unroll
  for (int c = 0; c < NCHUNK; ++c) {
    v += ws[OFF_C + (c * Lsz + i) * Asz + j];
    v += ws[OFF_G + ((size_t)(c * Lsz + i) * Bsz + b) * Asz + j];
  }
  l[b * 21 + j] = v;
  __syncthreads();

  if (t < Bsz) {
    float m = -1e30f;
    #pragma unroll
    for (int jj = 0; jj < Asz; ++jj) m = fmaxf(m, l[t * 21 + jj]);
    float se = 0.f;
    #pragma unroll
    for (int jj = 0; jj < Asz; ++jj) se += __expf(l[t * 21 + jj] - m);
    float lse = m + __logf(se);
    float en = wsng[i * Asz + x[t * Lsz + i]];
    #pragma unroll
    for (int c = 0; c < NCHUNK; ++c) en += ws[OFF_E + (c * Lsz + i) * Bsz + t];
    wso[OFF_K2 + i * Bsz + t] = lse - en;
  }
}

// Kernel 3: final scalar.
__global__ __launch_bounds__(256) void k3(const float* __restrict__ wsng,
                                          const float* __restrict__ ws,
                                          float* __restrict__ out) {
  const int t = threadIdx.x;
  float ssq = 0.f, sab = 0.f;
  for (int k = t; k < Lsz * Asz; k += 256) {
    float v = wsng[k];
    ssq += v * v; sab += fabsf(v);
  }
  float psq = 0.f, pab = 0.f;
  for (int k = t; k < NCHUNK * Lsz; k += 256) {
    psq += ws[OFF_RSQ + k];
    pab += ws[OFF_RAB + k];
  }
  float fe = 0.f;
  for (int k = t; k < Lsz * Bsz; k += 256) fe += ws[OFF_K2 + k];

  const float LP = 51.0f;  // 0.2 * (L-1)
  float val = fe * (1.0f / Bsz) + (ssq + sab) + LP * (psq + pab);

  __shared__ float red[256];
  red[t] = val;
  __syncthreads();
  for (int s = 128; s >= 1; s >>= 1) {
    if (t < s) red[t] += red[t + s];
    __syncthreads();
  }
  if (t == 0) out[0] = red[0];
}

extern "C" void kernel_launch(void* const* d_in, const int* in_sizes, int n_in,
                              void* d_out, int out_size, void* d_ws, size_t ws_size,
                              hipStream_t stream) {
  const int*   x       = (const int*)d_in[0];
  const float* wsingle = (const float*)d_in[1];
  const float* wpair   = (const float*)d_in[2];
  float* ws  = (float*)d_ws;
  float* out = (float*)d_out;

  k1<<<Lsz * NCHUNK, BLK1, 0, stream>>>(x, wpair, ws);
  k2<<<Lsz, BLK1, 0, stream>>>(x, wsingle, ws, ws);
  k3<<<1, 256, 0, stream>>>(wsingle, ws, out);
}